// Round 8
// baseline (36680.017 us; speedup 1.0000x reference)
//
#include <hip/hip_runtime.h>
#include <hip/hip_bf16.h>

// Problem: T=8192 steps, D_IN=2048, D=512 dense, H=512 cell, A=18 actions.
// out = concat(policy [T,18], value [T,1], hT [1,512]) fp32, 156160 elems.
//
// R7: R6's wave-3 publisher REGRESSED (+500cyc: mailbox hop delayed the
// publish). Store-ACK theory dead. Remaining cost = fabric round trips +
// WG-wide barrier coupling. This round: BARRIER-FREE wave-local exchange.
// Each wave is self-sufficient: lane l polls slots [8l,8l+8) with 8
// PARALLEL tagged loads, ds_writes values to a per-wave LDS pane, one
// lgkmcnt(0) (wave-level counter orders all 64 lanes' writes), reads its
// 32 matvec inputs back. No s_barrier in the loop; lockstep makes the
// pane race-free (step-s reads are consumed before step-s+1 writes issue).
// X prefetch sits right after detect, off every poll-wait path. Publish
// unchanged (proven R4 gate-lane immediate agent-scope store).

#define T_STEPS 8192
#define DIN 2048
#define DD 512
#define HHH 512
#define AACT 18
#define H3 1536
#define NWG 32          // worker WGs; each owns 16 rows of h

typedef __attribute__((ext_vector_type(8))) short short8;
typedef __attribute__((ext_vector_type(4))) float f32x4;

// ---------------------------------------------------------------- casts
__global__ void cast_f32_bf16(const float* __restrict__ in,
                              __hip_bfloat16* __restrict__ out, int n)
{
    int i = blockIdx.x * 256 + threadIdx.x;
    if (i < n) out[i] = __float2bfloat16(in[i]);
}

// ctl[2] = global abort flag (dead-man). ctl[0..1] unused.
__global__ void init_ctl(int* ctl) { ctl[0] = 0; ctl[1] = 0; ctl[2] = 0; }

// ---------------------------------------------------------------- GEMM
// C[M,N] = act(A[M,K] @ B[K,N] + bias). A either fp32 (cast on stage) or bf16.
// Block 256 (4 waves), tile 64x64, K-tile 32.
// MFMA 16x16x32 bf16: D: col=lane&15, row=quad*4+reg (verified m89/m91).
__global__ __launch_bounds__(256) void gemm_bf16(
    const float* __restrict__ A32, const __hip_bfloat16* __restrict__ A16,
    const __hip_bfloat16* __restrict__ B, const float* __restrict__ bias,
    __hip_bfloat16* __restrict__ Cb, float* __restrict__ Cf,
    int M, int N, int K, int relu)
{
    const int m0 = blockIdx.x * 64;
    const int n0 = blockIdx.y * 64;
    const int t  = threadIdx.x;
    const int wave = t >> 6;
    const int lane = t & 63;
    const int quad = lane >> 4;
    const int l16  = lane & 15;

    __shared__ __align__(16) __hip_bfloat16 As[64 * 40];
    __shared__ __align__(16) __hip_bfloat16 Bs[64 * 40];

    f32x4 acc[4];
#pragma unroll
    for (int c = 0; c < 4; ++c) acc[c] = (f32x4){0.f, 0.f, 0.f, 0.f};

    const int ar = t >> 2, akc = (t & 3) * 8;
    const int bk = t >> 3, bn  = (t & 7) * 8;

    for (int kb = 0; kb < K; kb += 32) {
        if (A32) {
            const float* src = A32 + (size_t)(m0 + ar) * K + kb + akc;
            float4 f0 = *(const float4*)(src);
            float4 f1 = *(const float4*)(src + 4);
            union { short8 v; __hip_bfloat16 h[8]; } u;
            u.h[0] = __float2bfloat16(f0.x); u.h[1] = __float2bfloat16(f0.y);
            u.h[2] = __float2bfloat16(f0.z); u.h[3] = __float2bfloat16(f0.w);
            u.h[4] = __float2bfloat16(f1.x); u.h[5] = __float2bfloat16(f1.y);
            u.h[6] = __float2bfloat16(f1.z); u.h[7] = __float2bfloat16(f1.w);
            *(short8*)&As[ar * 40 + akc] = u.v;
        } else {
            const __hip_bfloat16* src = A16 + (size_t)(m0 + ar) * K + kb + akc;
            *(short8*)&As[ar * 40 + akc] = *(const short8*)src;
        }
        {
            const __hip_bfloat16* src = B + (size_t)(kb + bk) * N + n0 + bn;
            short8 v = *(const short8*)src;
            const __hip_bfloat16* vh = (const __hip_bfloat16*)&v;
#pragma unroll
            for (int i = 0; i < 8; ++i) Bs[(bn + i) * 40 + bk] = vh[i];
        }
        __syncthreads();

        short8 a = *(const short8*)&As[(wave * 16 + l16) * 40 + quad * 8];
#pragma unroll
        for (int c = 0; c < 4; ++c) {
            short8 b = *(const short8*)&Bs[(c * 16 + l16) * 40 + quad * 8];
            acc[c] = __builtin_amdgcn_mfma_f32_16x16x32_bf16(a, b, acc[c], 0, 0, 0);
        }
        __syncthreads();
    }

#pragma unroll
    for (int c = 0; c < 4; ++c) {
        const int col = n0 + c * 16 + l16;
        const float bb = bias ? bias[col] : 0.f;
#pragma unroll
        for (int r = 0; r < 4; ++r) {
            const int row = m0 + wave * 16 + quad * 4 + r;
            float v = acc[c][r] + bb;
            if (relu) v = fmaxf(v, 0.f);
            if (Cb) Cb[(size_t)row * N + col] = __float2bfloat16(v);
            if (Cf) Cf[(size_t)row * N + col] = v;
        }
    }
}

// --------------------------------------------------------------- DPP reduce
// Reduce-to-lane0 within each 16-lane row via row_shl:N — lane i reads lane
// i+N; reads past the row end are 0-filled (bound_ctrl=true). Verified R3-R6.
template <int CTRL>
__device__ __forceinline__ float dpp_red_add(float x)
{
    int sh = __builtin_amdgcn_update_dpp(0, __float_as_int(x), CTRL, 0xF, 0xF, true);
    return x + __int_as_float(sh);
}

// ---------------------------------------------------------------- GRU scan
// 32 persistent WGs x 256 threads (waves_per_eu(1,1): WG alone on its CU).
// WG i owns h rows [16i,16i+16). Compute map: jl=t>>4 (row), kp=t&15
// (k-chunk [32kp,32kp+32)). Each WAVE (4 rows x 16 kp) is self-sufficient:
//   detect: lane l polls tagged slots [8l,8l+8) — 8 parallel 8B loads,
//           reissue only stale ones (compiler-exact vmcnt, proven R4 form);
//   stage:  4x ds_write_b64 into the wave's own LDS pane at
//           (k>>5)*36+(k&31) (chunk-major, 36-stride: conflict-light);
//   order:  one s_waitcnt lgkmcnt(0) — wave-level counter covers ALL
//           lanes' writes (lockstep) — then matvec reads its chunk.
// NO s_barrier in the loop. Pane reuse is lockstep-safe: step-s reads are
// consumed by FMAs (compiler lgkm waits) before step-s+1 writes issue.
// Exchange protocol unchanged (PROVEN): 8B tagged {f32 val, u32 step},
// parity double-buffer, RELAXED AGENT atomics; 0xAA poison never matches.
__global__ __launch_bounds__(256)
__attribute__((amdgpu_waves_per_eu(1, 1)))
void scan_kernel(
    const float* __restrict__ X,            // [T][1536] = z@Wg + bg[0]
    const float* __restrict__ Ug,           // [512][1536]
    const float* __restrict__ bg,           // [2][1536]; row 1 = recurrent bias
    const float* __restrict__ h0,           // [512] prev_hidden
    float* __restrict__ seq,                // [T][512]
    unsigned long long* __restrict__ hbuf,  // [2][512] tagged h (no init needed)
    float* __restrict__ hT,                 // [512] -> d_out tail
    int* __restrict__ ctl)                  // ctl[2] = abort flag
{
    const int t    = threadIdx.x;
    const int wg   = blockIdx.x;
    const int wave = t >> 6;
    const int l    = t & 63;
    const int jl   = t >> 4;
    const int kp   = t & 15;
    const int j    = wg * 16 + jl;
    const int k0   = kp * 32;

    // per-wave h pane: 16 chunks x 36 words (36-stride: read banks 2-way
    // aliased = free per m136). No double-buffer needed (lockstep-safe).
    __shared__ __align__(16) float hstage[4][16 * 36];
    __shared__ int wg_abort;
    if (t == 0) wg_abort = 0;
    __syncthreads();            // one-time init barrier only

    float wz[32], wr[32], wh[32];
#pragma unroll
    for (int m = 0; m < 32; ++m) {
        const float* row = Ug + (size_t)(k0 + m) * H3;
        wz[m] = row[j];
        wr[m] = row[512 + j];
        wh[m] = row[1024 + j];
    }
    // pin all 96 weights into AGPRs: guaranteed register residency for the
    // whole step loop (no scratch spill path exists for "a"-pinned values)
#pragma unroll
    for (int m = 0; m < 32; ++m) {
        asm volatile("" : "+a"(wz[m]), "+a"(wr[m]), "+a"(wh[m]));
    }

    const float* brec = bg + H3;
    const float bz = brec[j], brr = brec[512 + j], bh = brec[1024 + j];
    float hj = h0[j];  // my h element (kp==0 lanes)

    float* const hw = hstage[wave];
    // lane l stages values h[8l..8l+8) -> all land in chunk l>>2,
    // words 8*(l&3)..+8 (8l..8l+7 never crosses a 32-boundary)
    float* const wbase = hw + (l >> 2) * 36 + 8 * (l & 3);
    const int slot0 = l * 8;

    // prefetch X[0]
    float xz = 0.f, xr = 0.f, xh = 0.f;
    if (kp == 0) { xz = X[j]; xr = X[512 + j]; xh = X[1024 + j]; }

    for (int s = 0; s < T_STEPS; ++s) {
        // ---- detect + stage my 8 slots
        if (s == 0) {
            float4 a = *(const float4*)(h0 + slot0);
            float4 b = *(const float4*)(h0 + slot0 + 4);
            *(float2*)(wbase + 0) = make_float2(a.x, a.y);
            *(float2*)(wbase + 2) = make_float2(a.z, a.w);
            *(float2*)(wbase + 4) = make_float2(b.x, b.y);
            *(float2*)(wbase + 6) = make_float2(b.z, b.w);
        } else {
            const unsigned long long* src = hbuf + ((size_t)(s & 1) << 9) + slot0;
            unsigned long long v[8];
            bool ok[8];
#pragma unroll
            for (int i = 0; i < 8; ++i) {
                v[i] = __hip_atomic_load(src + i, __ATOMIC_RELAXED, __HIP_MEMORY_SCOPE_AGENT);
                ok[i] = false;
            }
            int guard = 0;
            bool bail = false;
            for (;;) {
                bool all = true;
#pragma unroll
                for (int i = 0; i < 8; ++i) {
                    if (!ok[i]) {
                        if ((unsigned)(v[i] >> 32) == (unsigned)s) ok[i] = true;
                        else all = false;
                    }
                }
                if (all) break;
#pragma unroll
                for (int i = 0; i < 8; ++i)
                    if (!ok[i]) v[i] = __hip_atomic_load(src + i, __ATOMIC_RELAXED, __HIP_MEMORY_SCOPE_AGENT);
                if ((++guard & 1023) == 0) {       // dead-man / global abort
                    int ab = __hip_atomic_load(ctl + 2, __ATOMIC_RELAXED,
                                               __HIP_MEMORY_SCOPE_AGENT);
                    if (ab || *(volatile int*)&wg_abort || guard > (1 << 16)) {
                        bail = true;
                        break;
                    }
                }
            }
            if (__any(bail)) {                     // wave-uniform fail-fast
                *(volatile int*)&wg_abort = 1;
                if (l == 0)
                    __hip_atomic_store(ctl + 2, 1, __ATOMIC_RELAXED,
                                       __HIP_MEMORY_SCOPE_AGENT);
                return;
            }
            *(float2*)(wbase + 0) = make_float2(__uint_as_float((unsigned)v[0]),
                                                __uint_as_float((unsigned)v[1]));
            *(float2*)(wbase + 2) = make_float2(__uint_as_float((unsigned)v[2]),
                                                __uint_as_float((unsigned)v[3]));
            *(float2*)(wbase + 4) = make_float2(__uint_as_float((unsigned)v[4]),
                                                __uint_as_float((unsigned)v[5]));
            *(float2*)(wbase + 6) = make_float2(__uint_as_float((unsigned)v[6]),
                                                __uint_as_float((unsigned)v[7]));
        }

        // ---- X[s+1] prefetch: issued right after detect, soaks under
        //      stage-wait + matvec + publish (off every poll-wait path)
        float nxz = 0.f, nxr = 0.f, nxh = 0.f;
        if (kp == 0 && s + 1 < T_STEPS) {
            const float* Xs = X + (size_t)(s + 1) * H3;
            nxz = Xs[j]; nxr = Xs[512 + j]; nxh = Xs[1024 + j];
        }

        // ---- wave-level write->read ordering: lgkmcnt is a WAVE counter,
        //      so one wait covers all 64 lanes' ds_writes (lockstep).
        asm volatile("s_waitcnt lgkmcnt(0)" ::: "memory");
        __builtin_amdgcn_sched_barrier(0);

        // ---- partial matvec: 32 k-values x 3 gate columns
        float accz = 0.f, accr = 0.f, acch = 0.f;
        const float* hb = hw + kp * 36;
#pragma unroll
        for (int m = 0; m < 32; m += 4) {
            float4 hv = *(const float4*)(hb + m);
            accz = fmaf(hv.x, wz[m    ], accz);
            accz = fmaf(hv.y, wz[m + 1], accz);
            accz = fmaf(hv.z, wz[m + 2], accz);
            accz = fmaf(hv.w, wz[m + 3], accz);
            accr = fmaf(hv.x, wr[m    ], accr);
            accr = fmaf(hv.y, wr[m + 1], accr);
            accr = fmaf(hv.z, wr[m + 2], accr);
            accr = fmaf(hv.w, wr[m + 3], accr);
            acch = fmaf(hv.x, wh[m    ], acch);
            acch = fmaf(hv.y, wh[m + 1], acch);
            acch = fmaf(hv.z, wh[m + 2], acch);
            acch = fmaf(hv.w, wh[m + 3], acch);
        }
        // reduce across the 16 kp lanes: VALU-only DPP row_shl tree,
        // sum accumulates INTO lane 0 of each 16-lane row (= kp==0)
        accz = dpp_red_add<0x108>(accz);  // += lane+8
        accr = dpp_red_add<0x108>(accr);
        acch = dpp_red_add<0x108>(acch);
        accz = dpp_red_add<0x104>(accz);  // += lane+4
        accr = dpp_red_add<0x104>(accr);
        acch = dpp_red_add<0x104>(acch);
        accz = dpp_red_add<0x102>(accz);  // += lane+2
        accr = dpp_red_add<0x102>(accr);
        acch = dpp_red_add<0x102>(acch);
        accz = dpp_red_add<0x101>(accz);  // += lane+1
        accr = dpp_red_add<0x101>(accr);
        acch = dpp_red_add<0x101>(acch);

        if (kp == 0) {
            const float rz = accz + bz, rr = accr + brr, rh = acch + bh;
            const float zt = 1.f / (1.f + __expf(-(xz + rz)));
            const float rt = 1.f / (1.f + __expf(-(xr + rr)));
            const float hc = 1.f / (1.f + __expf(-(xh + rt * rh)));
            const float hn = zt * hj + (1.f - zt) * hc;
            hj = hn;
            // publish FIRST and IMMEDIATELY (proven R4 form): this store is
            // the device-wide critical path
            unsigned long long pk =
                ((unsigned long long)(unsigned)(s + 1) << 32) | (unsigned)__float_as_uint(hn);
            __hip_atomic_store(hbuf + (size_t)(((s + 1) & 1) << 9) + j, pk,
                               __ATOMIC_RELAXED, __HIP_MEMORY_SCOPE_AGENT);
            seq[(size_t)s * HHH + j] = hn;
            if (s == T_STEPS - 1) hT[j] = hn;
        }
        xz = nxz; xr = nxr; xh = nxh;
        // no trailing barrier: waves are fully independent
    }
}

// ---------------------------------------------------------------- heads
__global__ __launch_bounds__(64) void heads_kernel(
    const float* __restrict__ seq, const float* __restrict__ Wp,
    const float* __restrict__ bp, const float* __restrict__ Wv,
    const float* __restrict__ bv, float* __restrict__ pol,
    float* __restrict__ val)
{
    const int s = blockIdx.x;
    const int l = threadIdx.x;
    const float* h = seq + (size_t)s * HHH;

    float acc[19];
#pragma unroll
    for (int jj = 0; jj < 19; ++jj) acc[jj] = 0.f;

#pragma unroll
    for (int kk = 0; kk < 8; ++kk) {
        const int k = kk * 64 + l;
        const float hv = h[k];
        const float* wrow = Wp + (size_t)k * AACT;
#pragma unroll
        for (int jj = 0; jj < AACT; ++jj) acc[jj] = fmaf(hv, wrow[jj], acc[jj]);
        acc[18] = fmaf(hv, Wv[k], acc[18]);
    }
#pragma unroll
    for (int jj = 0; jj < 19; ++jj) {
        float v = acc[jj];
#pragma unroll
        for (int off = 32; off; off >>= 1) v += __shfl_down(v, off, 64);
        acc[jj] = v;
    }
    if (l == 0) {
        float lg[18], mx = -1e30f;
#pragma unroll
        for (int jj = 0; jj < AACT; ++jj) { lg[jj] = acc[jj] + bp[jj]; mx = fmaxf(mx, lg[jj]); }
        float sum = 0.f;
#pragma unroll
        for (int jj = 0; jj < AACT; ++jj) { lg[jj] = __expf(lg[jj] - mx); sum += lg[jj]; }
        const float inv = 1.f / sum;
#pragma unroll
        for (int jj = 0; jj < AACT; ++jj) pol[(size_t)s * AACT + jj] = lg[jj] * inv;
        val[s] = acc[18] + bv[0];
    }
}

// ---------------------------------------------------------------- launch
extern "C" void kernel_launch(void* const* d_in, const int* in_sizes, int n_in,
                              void* d_out, int out_size, void* d_ws, size_t ws_size,
                              hipStream_t stream)
{
    const float* x  = (const float*)d_in[0];
    const float* h0 = (const float*)d_in[1];
    const float* W1 = (const float*)d_in[2];
    const float* b1 = (const float*)d_in[3];
    const float* W2 = (const float*)d_in[4];
    const float* b2 = (const float*)d_in[5];
    const float* Wg = (const float*)d_in[6];
    const float* Ug = (const float*)d_in[7];
    const float* bg = (const float*)d_in[8];
    const float* Wp = (const float*)d_in[9];
    const float* bp = (const float*)d_in[10];
    const float* Wv = (const float*)d_in[11];
    const float* bv = (const float*)d_in[12];

    char* ws = (char*)d_ws;
    __hip_bfloat16* W1b = (__hip_bfloat16*)(ws + 0);         // 2,097,152
    __hip_bfloat16* W2b = (__hip_bfloat16*)(ws + 2097152);   //   524,288
    __hip_bfloat16* Wgb = (__hip_bfloat16*)(ws + 2621440);   // 1,572,864
    __hip_bfloat16* z1b = (__hip_bfloat16*)(ws + 4194304);   // 8,388,608
    __hip_bfloat16* z2b = (__hip_bfloat16*)(ws + 12582912);  // 8,388,608
    float*          Xb  = (float*)(ws + 20971520);           // 50,331,648
    float*          seq = (float*)(ws + 71303168);           // 16,777,216
    unsigned long long* hbuf = (unsigned long long*)(ws + 88080384); // 8,192
    // hbuf needs NO init: step tags are self-validating vs 0xAA poison.
    // ctl carved from z1b (dead after gemm2 reads it; init_ctl is
    // stream-ordered after the gemms, before scan) — zero extra ws footprint.
    int* ctl = (int*)(ws + 4194304);

    float* out = (float*)d_out;
    float* pol = out;
    float* val = out + (size_t)T_STEPS * AACT;
    float* hT  = out + (size_t)T_STEPS * AACT + T_STEPS;

    cast_f32_bf16<<<DIN * DD / 256, 256, 0, stream>>>(W1, W1b, DIN * DD);
    cast_f32_bf16<<<DD * DD / 256, 256, 0, stream>>>(W2, W2b, DD * DD);
    cast_f32_bf16<<<DD * H3 / 256, 256, 0, stream>>>(Wg, Wgb, DD * H3);

    dim3 blk(256);
    gemm_bf16<<<dim3(T_STEPS / 64, DD / 64), blk, 0, stream>>>(
        x, nullptr, W1b, b1, z1b, nullptr, T_STEPS, DD, DIN, 1);
    gemm_bf16<<<dim3(T_STEPS / 64, DD / 64), blk, 0, stream>>>(
        nullptr, z1b, W2b, b2, z2b, nullptr, T_STEPS, DD, DD, 1);
    gemm_bf16<<<dim3(T_STEPS / 64, H3 / 64), blk, 0, stream>>>(
        nullptr, z2b, Wgb, bg, nullptr, Xb, T_STEPS, H3, DD, 0);

    init_ctl<<<1, 1, 0, stream>>>(ctl);
    scan_kernel<<<NWG, 256, 0, stream>>>(Xb, Ug, bg, h0, seq, hbuf, hT, ctl);

    heads_kernel<<<T_STEPS, 64, 0, stream>>>(seq, Wp, bp, Wv, bv, pol, val);
}

// Round 9
// 12193.346 us; speedup vs baseline: 3.0082x; 3.0082x over previous
//
#include <hip/hip_runtime.h>
#include <hip/hip_bf16.h>

// Problem: T=8192 steps, D_IN=2048, D=512 dense, H=512 cell, A=18 actions.
// out = concat(policy [T,18], value [T,1], hT [1,512]) fp32, 156160 elems.
//
// R8: R7 (wave-local 8-slot polling, no barrier) regressed 3x — reverted to
// the R5 structure (proven best, scan ~12.0ms). R5's counters show the
// exchange runs at HBM latency: FETCH 186MB includes ~130MB of poll
// refetches (polls MISS L3 -> HBM, ~900cyc quantum) and WRITE 49MB includes
// 33MB of hbuf write-through (512x8Bx8192 exactly). This round changes ONLY
// the memory-op flavor of the exchange so it executes at the COHERENCE
// POINT (memory-side cache atomic units) instead of HBM:
//   publish: atomic_exchange (result unused -> global_atomic_swap, no ret)
//   poll:    atomic_fetch_or(slot, 0) — read-as-RMW at the coherence point
// Everything else byte-identical to R5.

#define T_STEPS 8192
#define DIN 2048
#define DD 512
#define HHH 512
#define AACT 18
#define H3 1536
#define NWG 32          // worker WGs; each owns 16 rows of h

typedef __attribute__((ext_vector_type(8))) short short8;
typedef __attribute__((ext_vector_type(4))) float f32x4;

typedef unsigned long long u64;

// ---------------------------------------------------------------- casts
__global__ void cast_f32_bf16(const float* __restrict__ in,
                              __hip_bfloat16* __restrict__ out, int n)
{
    int i = blockIdx.x * 256 + threadIdx.x;
    if (i < n) out[i] = __float2bfloat16(in[i]);
}

// ctl[2] = global abort flag (dead-man). ctl[0..1] unused.
__global__ void init_ctl(int* ctl) { ctl[0] = 0; ctl[1] = 0; ctl[2] = 0; }

// ---------------------------------------------------------------- GEMM
// C[M,N] = act(A[M,K] @ B[K,N] + bias). A either fp32 (cast on stage) or bf16.
// Block 256 (4 waves), tile 64x64, K-tile 32.
// MFMA 16x16x32 bf16: D: col=lane&15, row=quad*4+reg (verified m89/m91).
__global__ __launch_bounds__(256) void gemm_bf16(
    const float* __restrict__ A32, const __hip_bfloat16* __restrict__ A16,
    const __hip_bfloat16* __restrict__ B, const float* __restrict__ bias,
    __hip_bfloat16* __restrict__ Cb, float* __restrict__ Cf,
    int M, int N, int K, int relu)
{
    const int m0 = blockIdx.x * 64;
    const int n0 = blockIdx.y * 64;
    const int t  = threadIdx.x;
    const int wave = t >> 6;
    const int lane = t & 63;
    const int quad = lane >> 4;
    const int l16  = lane & 15;

    __shared__ __align__(16) __hip_bfloat16 As[64 * 40];
    __shared__ __align__(16) __hip_bfloat16 Bs[64 * 40];

    f32x4 acc[4];
#pragma unroll
    for (int c = 0; c < 4; ++c) acc[c] = (f32x4){0.f, 0.f, 0.f, 0.f};

    const int ar = t >> 2, akc = (t & 3) * 8;
    const int bk = t >> 3, bn  = (t & 7) * 8;

    for (int kb = 0; kb < K; kb += 32) {
        if (A32) {
            const float* src = A32 + (size_t)(m0 + ar) * K + kb + akc;
            float4 f0 = *(const float4*)(src);
            float4 f1 = *(const float4*)(src + 4);
            union { short8 v; __hip_bfloat16 h[8]; } u;
            u.h[0] = __float2bfloat16(f0.x); u.h[1] = __float2bfloat16(f0.y);
            u.h[2] = __float2bfloat16(f0.z); u.h[3] = __float2bfloat16(f0.w);
            u.h[4] = __float2bfloat16(f1.x); u.h[5] = __float2bfloat16(f1.y);
            u.h[6] = __float2bfloat16(f1.z); u.h[7] = __float2bfloat16(f1.w);
            *(short8*)&As[ar * 40 + akc] = u.v;
        } else {
            const __hip_bfloat16* src = A16 + (size_t)(m0 + ar) * K + kb + akc;
            *(short8*)&As[ar * 40 + akc] = *(const short8*)src;
        }
        {
            const __hip_bfloat16* src = B + (size_t)(kb + bk) * N + n0 + bn;
            short8 v = *(const short8*)src;
            const __hip_bfloat16* vh = (const __hip_bfloat16*)&v;
#pragma unroll
            for (int i = 0; i < 8; ++i) Bs[(bn + i) * 40 + bk] = vh[i];
        }
        __syncthreads();

        short8 a = *(const short8*)&As[(wave * 16 + l16) * 40 + quad * 8];
#pragma unroll
        for (int c = 0; c < 4; ++c) {
            short8 b = *(const short8*)&Bs[(c * 16 + l16) * 40 + quad * 8];
            acc[c] = __builtin_amdgcn_mfma_f32_16x16x32_bf16(a, b, acc[c], 0, 0, 0);
        }
        __syncthreads();
    }

#pragma unroll
    for (int c = 0; c < 4; ++c) {
        const int col = n0 + c * 16 + l16;
        const float bb = bias ? bias[col] : 0.f;
#pragma unroll
        for (int r = 0; r < 4; ++r) {
            const int row = m0 + wave * 16 + quad * 4 + r;
            float v = acc[c][r] + bb;
            if (relu) v = fmaxf(v, 0.f);
            if (Cb) Cb[(size_t)row * N + col] = __float2bfloat16(v);
            if (Cf) Cf[(size_t)row * N + col] = v;
        }
    }
}

// --------------------------------------------------------------- DPP reduce
// Reduce-to-lane0 within each 16-lane row via row_shl:N — lane i reads lane
// i+N; reads past the row end are 0-filled (bound_ctrl=true). Verified R3-R7.
template <int CTRL>
__device__ __forceinline__ float dpp_red_add(float x)
{
    int sh = __builtin_amdgcn_update_dpp(0, __float_as_int(x), CTRL, 0xF, 0xF, true);
    return x + __int_as_float(sh);
}

// LDS-only barrier: orders ds ops (lgkmcnt) but does NOT drain vmcnt —
// global loads/stores/atomics stay in flight across it (verified R5).
__device__ __forceinline__ void wg_barrier_lds_only()
{
    asm volatile("s_waitcnt lgkmcnt(0)" ::: "memory");
    __builtin_amdgcn_s_barrier();
    asm volatile("" ::: "memory");
}

// coherence-point read: RMW-or-0 executed at the memory-side atomic unit
// (not an L1/L2/write-through-HBM load path)
__device__ __forceinline__ u64 cp_read(u64* p)
{
    return __hip_atomic_fetch_or(p, 0ull, __ATOMIC_RELAXED,
                                 __HIP_MEMORY_SCOPE_AGENT);
}

// ---------------------------------------------------------------- GRU scan
// 32 persistent WGs x 256 threads (waves_per_eu(1,1): WG alone on its CU).
// WG i owns h rows [16i, 16i+16). Thread t: jl=t>>4 (row), kp=t&15
// (k-chunk [32kp, 32kp+32)).
// h exchange: 8B tagged slots {f32 val, u32 step}, parity double-buffer —
// protocol semantics PROVEN (R4/R5); this round only swaps the memory-op
// flavor to coherence-point atomics (see header). Dual staggered sample
// chains (~L/2 apart) as in R5. Tags self-validating; 0xAA never matches.
__global__ __launch_bounds__(256)
__attribute__((amdgpu_waves_per_eu(1, 1)))
void scan_kernel(
    const float* __restrict__ X,            // [T][1536] = z@Wg + bg[0]
    const float* __restrict__ Ug,           // [512][1536]
    const float* __restrict__ bg,           // [2][1536]; row 1 = recurrent bias
    const float* __restrict__ h0,           // [512] prev_hidden
    float* __restrict__ seq,                // [T][512]
    u64* __restrict__ hbuf,                 // [2][512] tagged h (no init needed)
    float* __restrict__ hT,                 // [512] -> d_out tail
    int* __restrict__ ctl)                  // ctl[2] = abort flag
{
    const int t  = threadIdx.x;
    const int wg = blockIdx.x;
    const int jl = t >> 4;
    const int kp = t & 15;
    const int j  = wg * 16 + jl;
    const int k0 = kp * 32;

    // double-buffered h stage; row stride 36 words = 144B (16B aligned;
    // b128 reads across 16 kp-lanes alias banks 2-way = free per m136)
    __shared__ __align__(16) float h_lds[2][16 * 36];
    __shared__ int wg_abort;
    if (t == 0) wg_abort = 0;

    float wz[32], wr[32], wh[32];
#pragma unroll
    for (int m = 0; m < 32; ++m) {
        const float* row = Ug + (size_t)(k0 + m) * H3;
        wz[m] = row[j];
        wr[m] = row[512 + j];
        wh[m] = row[1024 + j];
    }
    // pin all 96 weights into AGPRs: guaranteed register residency for the
    // whole step loop (no scratch spill path exists for "a"-pinned values)
#pragma unroll
    for (int m = 0; m < 32; ++m) {
        asm volatile("" : "+a"(wz[m]), "+a"(wr[m]), "+a"(wh[m]));
    }

    const float* brec = bg + H3;
    const float bz = brec[j], brr = brec[512 + j], bh = brec[1024 + j];
    float hj = h0[j];  // my h element (kp==0 lanes)

    // staging slots for this thread (thread t owns k1, k2)
    const int k1 = t, k2 = t + 256;
    const int la1 = (k1 >> 5) * 36 + (k1 & 31);
    const int la2 = (k2 >> 5) * 36 + (k2 & 31);

    // prefetch X[0]
    float xz = 0.f, xr = 0.f, xh = 0.f;
    if (kp == 0) { xz = X[j]; xr = X[512 + j]; xh = X[1024 + j]; }

    for (int s = 0; s < T_STEPS; ++s) {
        float* hl = h_lds[s & 1];

        // ---- prefetch X[s+1] FIRST: retires under the spin
        float nxz = 0.f, nxr = 0.f, nxh = 0.f;
        if (kp == 0 && s + 1 < T_STEPS) {
            const float* Xs = X + (size_t)(s + 1) * H3;
            nxz = Xs[j]; nxr = Xs[512 + j]; nxh = Xs[1024 + j];
        }

        // ---- acquire h_s: dual staggered sample chains, coherence-point reads
        if (s == 0) {
            hl[la1] = h0[k1];
            hl[la2] = h0[k2];
        } else {
            u64* src = hbuf + ((size_t)(s & 1) << 9);
            u64 v1 = 0, v2 = 0;
            // chain A sample
            u64 a1 = cp_read(src + k1);
            u64 a2 = cp_read(src + k2);
            // ~L/2 stagger so A/B sample the slot out of phase
            asm volatile("" ::: "memory");
            __builtin_amdgcn_s_sleep(4);          // ~256 cyc
            asm volatile("" ::: "memory");
            // chain B sample
            u64 b1 = cp_read(src + k1);
            u64 b2 = cp_read(src + k2);
            bool ok1 = false, ok2 = false;
            int guard = 0;
            for (;;) {
                // phase A: consume chain-A sample (waits A only; B in flight)
                if (!ok1 && (unsigned)(a1 >> 32) == (unsigned)s) { v1 = a1; ok1 = true; }
                if (!ok2 && (unsigned)(a2 >> 32) == (unsigned)s) { v2 = a2; ok2 = true; }
                if (ok1 && ok2) break;
                if (!ok1) a1 = cp_read(src + k1);
                if (!ok2) a2 = cp_read(src + k2);
                // phase B: consume chain-B sample (~L/2 later)
                if (!ok1 && (unsigned)(b1 >> 32) == (unsigned)s) { v1 = b1; ok1 = true; }
                if (!ok2 && (unsigned)(b2 >> 32) == (unsigned)s) { v2 = b2; ok2 = true; }
                if (ok1 && ok2) break;
                if (!ok1) b1 = cp_read(src + k1);
                if (!ok2) b2 = cp_read(src + k2);
                if ((++guard & 511) == 0) {        // dead-man / global abort
                    int ab = __hip_atomic_load(ctl + 2, __ATOMIC_RELAXED,
                                               __HIP_MEMORY_SCOPE_AGENT);
                    if (ab || guard > (1 << 16)) {
                        wg_abort = 1;
                        __hip_atomic_store(ctl + 2, 1, __ATOMIC_RELAXED,
                                           __HIP_MEMORY_SCOPE_AGENT);
                        break;
                    }
                }
            }
            hl[la1] = __uint_as_float((unsigned)v1);
            hl[la2] = __uint_as_float((unsigned)v2);
        }
        wg_barrier_lds_only();
        if (wg_abort) return;   // uniform exit: no barrier divergence

        // ---- partial matvec: 32 k-values x 3 gate columns
        float accz = 0.f, accr = 0.f, acch = 0.f;
        const float* hb = &hl[kp * 36];
#pragma unroll
        for (int m = 0; m < 32; m += 4) {
            float4 hv = *(const float4*)(hb + m);
            accz = fmaf(hv.x, wz[m    ], accz);
            accz = fmaf(hv.y, wz[m + 1], accz);
            accz = fmaf(hv.z, wz[m + 2], accz);
            accz = fmaf(hv.w, wz[m + 3], accz);
            accr = fmaf(hv.x, wr[m    ], accr);
            accr = fmaf(hv.y, wr[m + 1], accr);
            accr = fmaf(hv.z, wr[m + 2], accr);
            accr = fmaf(hv.w, wr[m + 3], accr);
            acch = fmaf(hv.x, wh[m    ], acch);
            acch = fmaf(hv.y, wh[m + 1], acch);
            acch = fmaf(hv.z, wh[m + 2], acch);
            acch = fmaf(hv.w, wh[m + 3], acch);
        }
        // reduce across the 16 kp lanes: VALU-only DPP row_shl tree,
        // sum accumulates INTO lane 0 of each 16-lane row (= kp==0)
        accz = dpp_red_add<0x108>(accz);  // += lane+8
        accr = dpp_red_add<0x108>(accr);
        acch = dpp_red_add<0x108>(acch);
        accz = dpp_red_add<0x104>(accz);  // += lane+4
        accr = dpp_red_add<0x104>(accr);
        acch = dpp_red_add<0x104>(acch);
        accz = dpp_red_add<0x102>(accz);  // += lane+2
        accr = dpp_red_add<0x102>(accr);
        acch = dpp_red_add<0x102>(acch);
        accz = dpp_red_add<0x101>(accz);  // += lane+1
        accr = dpp_red_add<0x101>(accr);
        acch = dpp_red_add<0x101>(acch);

        if (kp == 0) {
            const float rz = accz + bz, rr = accr + brr, rh = acch + bh;
            const float zt = 1.f / (1.f + __expf(-(xz + rz)));
            const float rt = 1.f / (1.f + __expf(-(xr + rr)));
            const float hc = 1.f / (1.f + __expf(-(xh + rt * rh)));
            const float hn = zt * hj + (1.f - zt) * hc;
            hj = hn;
            // publish FIRST and IMMEDIATELY: atomic swap executes at the
            // coherence point (result unused -> no return wait); this is the
            // device-wide critical path
            u64 pk = ((u64)(unsigned)(s + 1) << 32) | (unsigned)__float_as_uint(hn);
            (void)__hip_atomic_exchange(
                hbuf + (size_t)(((s + 1) & 1) << 9) + j, pk,
                __ATOMIC_RELAXED, __HIP_MEMORY_SCOPE_AGENT);
            seq[(size_t)s * HHH + j] = hn;
            if (s == T_STEPS - 1) hT[j] = hn;
        }
        xz = nxz; xr = nxr; xh = nxh;
        // no trailing barrier: LDS double-buffered; next iter syncs after stage
    }
}

// ---------------------------------------------------------------- heads
__global__ __launch_bounds__(64) void heads_kernel(
    const float* __restrict__ seq, const float* __restrict__ Wp,
    const float* __restrict__ bp, const float* __restrict__ Wv,
    const float* __restrict__ bv, float* __restrict__ pol,
    float* __restrict__ val)
{
    const int s = blockIdx.x;
    const int l = threadIdx.x;
    const float* h = seq + (size_t)s * HHH;

    float acc[19];
#pragma unroll
    for (int jj = 0; jj < 19; ++jj) acc[jj] = 0.f;

#pragma unroll
    for (int kk = 0; kk < 8; ++kk) {
        const int k = kk * 64 + l;
        const float hv = h[k];
        const float* wrow = Wp + (size_t)k * AACT;
#pragma unroll
        for (int jj = 0; jj < AACT; ++jj) acc[jj] = fmaf(hv, wrow[jj], acc[jj]);
        acc[18] = fmaf(hv, Wv[k], acc[18]);
    }
#pragma unroll
    for (int jj = 0; jj < 19; ++jj) {
        float v = acc[jj];
#pragma unroll
        for (int off = 32; off; off >>= 1) v += __shfl_down(v, off, 64);
        acc[jj] = v;
    }
    if (l == 0) {
        float lg[18], mx = -1e30f;
#pragma unroll
        for (int jj = 0; jj < AACT; ++jj) { lg[jj] = acc[jj] + bp[jj]; mx = fmaxf(mx, lg[jj]); }
        float sum = 0.f;
#pragma unroll
        for (int jj = 0; jj < AACT; ++jj) { lg[jj] = __expf(lg[jj] - mx); sum += lg[jj]; }
        const float inv = 1.f / sum;
#pragma unroll
        for (int jj = 0; jj < AACT; ++jj) pol[(size_t)s * AACT + jj] = lg[jj] * inv;
        val[s] = acc[18] + bv[0];
    }
}

// ---------------------------------------------------------------- launch
extern "C" void kernel_launch(void* const* d_in, const int* in_sizes, int n_in,
                              void* d_out, int out_size, void* d_ws, size_t ws_size,
                              hipStream_t stream)
{
    const float* x  = (const float*)d_in[0];
    const float* h0 = (const float*)d_in[1];
    const float* W1 = (const float*)d_in[2];
    const float* b1 = (const float*)d_in[3];
    const float* W2 = (const float*)d_in[4];
    const float* b2 = (const float*)d_in[5];
    const float* Wg = (const float*)d_in[6];
    const float* Ug = (const float*)d_in[7];
    const float* bg = (const float*)d_in[8];
    const float* Wp = (const float*)d_in[9];
    const float* bp = (const float*)d_in[10];
    const float* Wv = (const float*)d_in[11];
    const float* bv = (const float*)d_in[12];

    char* ws = (char*)d_ws;
    __hip_bfloat16* W1b = (__hip_bfloat16*)(ws + 0);         // 2,097,152
    __hip_bfloat16* W2b = (__hip_bfloat16*)(ws + 2097152);   //   524,288
    __hip_bfloat16* Wgb = (__hip_bfloat16*)(ws + 2621440);   // 1,572,864
    __hip_bfloat16* z1b = (__hip_bfloat16*)(ws + 4194304);   // 8,388,608
    __hip_bfloat16* z2b = (__hip_bfloat16*)(ws + 12582912);  // 8,388,608
    float*          Xb  = (float*)(ws + 20971520);           // 50,331,648
    float*          seq = (float*)(ws + 71303168);           // 16,777,216
    u64*            hbuf = (u64*)(ws + 88080384);            // 8,192
    // hbuf needs NO init: step tags are self-validating vs 0xAA poison.
    // ctl carved from z1b (dead after gemm2 reads it; init_ctl is
    // stream-ordered after the gemms, before scan) — zero extra ws footprint.
    int* ctl = (int*)(ws + 4194304);

    float* out = (float*)d_out;
    float* pol = out;
    float* val = out + (size_t)T_STEPS * AACT;
    float* hT  = out + (size_t)T_STEPS * AACT + T_STEPS;

    cast_f32_bf16<<<DIN * DD / 256, 256, 0, stream>>>(W1, W1b, DIN * DD);
    cast_f32_bf16<<<DD * DD / 256, 256, 0, stream>>>(W2, W2b, DD * DD);
    cast_f32_bf16<<<DD * H3 / 256, 256, 0, stream>>>(Wg, Wgb, DD * H3);

    dim3 blk(256);
    gemm_bf16<<<dim3(T_STEPS / 64, DD / 64), blk, 0, stream>>>(
        x, nullptr, W1b, b1, z1b, nullptr, T_STEPS, DD, DIN, 1);
    gemm_bf16<<<dim3(T_STEPS / 64, DD / 64), blk, 0, stream>>>(
        nullptr, z1b, W2b, b2, z2b, nullptr, T_STEPS, DD, DD, 1);
    gemm_bf16<<<dim3(T_STEPS / 64, H3 / 64), blk, 0, stream>>>(
        nullptr, z2b, Wgb, bg, nullptr, Xb, T_STEPS, H3, DD, 0);

    init_ctl<<<1, 1, 0, stream>>>(ctl);
    scan_kernel<<<NWG, 256, 0, stream>>>(Xb, Ug, bg, h0, seq, hbuf, hT, ctl);

    heads_kernel<<<T_STEPS, 64, 0, stream>>>(seq, Wp, bp, Wv, bv, pol, val);
}